// Round 6
// baseline (181.016 us; speedup 1.0000x reference)
//
#include <hip/hip_runtime.h>
#include <hip/hip_bf16.h>

#define TB 8
#define TT 4096
#define TC 1024
#define THS 128

typedef __bf16 bf16;
typedef __attribute__((ext_vector_type(8))) __bf16 bf16x8;
typedef __attribute__((ext_vector_type(2))) __bf16 bf16x2;
typedef __attribute__((ext_vector_type(4))) float f32x4;
typedef __attribute__((ext_vector_type(16))) float f32x16;

__device__ __forceinline__ unsigned pkbf(float a, float b) {
    bf16x2 t = { (bf16)a, (bf16)b };
    return __builtin_bit_cast(unsigned, t);
}

__device__ __forceinline__ void gload16(const void* g, void* l) {
    __builtin_amdgcn_global_load_lds(
        (const __attribute__((address_space(1))) void*)g,
        (__attribute__((address_space(3))) void*)l, 16, 0, 0);
}

// ---- W cast+transpose via LDS tile: Wt[w][n][k] = bf16(W_w[k][n]) ----
__global__ __launch_bounds__(256) void wt_kernel(const float* __restrict__ Wq,
                                                 const float* __restrict__ Wk,
                                                 const float* __restrict__ Wv,
                                                 bf16* __restrict__ Wt) {
    __shared__ float tile[64][65];
    const int tid = threadIdx.x;
    const int idx = blockIdx.x;                  // 96 blocks: w*32 + kt*2 + ntb
    const int w = idx >> 5;
    const int kt = (idx & 31) >> 1, ntb = idx & 1;
    const int k0 = kt * 64, n0 = ntb * 64;
    const float* W = (w == 0) ? Wq : (w == 1) ? Wk : Wv;
    #pragma unroll
    for (int i = 0; i < 4; i++) {                // 64x64 f32 tile, coalesced rows
        int r = (tid >> 4) + i * 16;
        int c4 = (tid & 15) * 4;
        float4 x4 = *reinterpret_cast<const float4*>(&W[(long)(k0 + r) * 128 + n0 + c4]);
        tile[r][c4 + 0] = x4.x; tile[r][c4 + 1] = x4.y;
        tile[r][c4 + 2] = x4.z; tile[r][c4 + 3] = x4.w;
    }
    __syncthreads();
    const int n = tid >> 2, kk = (tid & 3) * 16;
    bf16 o[16];
    #pragma unroll
    for (int j = 0; j < 16; j++) o[j] = (bf16)tile[kk + j][n];
    bf16* dst = &Wt[(long)((w << 7) + n0 + n) * 1024 + k0 + kk];
    *reinterpret_cast<bf16x8*>(dst)     = *reinterpret_cast<bf16x8*>(&o[0]);
    *reinterpret_cast<bf16x8*>(dst + 8) = *reinterpret_cast<bf16x8*>(&o[8]);
}

// ---- fused QKV projection (unchanged from round 5) ----
__global__ __launch_bounds__(256, 2) void qkv_kernel(const float* __restrict__ x,
                                                     const bf16* __restrict__ Wt,
                                                     bf16* __restrict__ Q,
                                                     bf16* __restrict__ K,
                                                     bf16* __restrict__ V) {
    __shared__ __align__(1024) char wsm[2][24576];
    __shared__ __align__(1024) char xsm[2][8192];
    const int tid = threadIdx.x;
    const int wave = tid >> 6, lane = tid & 63;
    const int lr = lane & 15, g = lane >> 4;
    const long row0 = (long)blockIdx.x * 64;

    long wOff[6]; int wLoff[6];
    #pragma unroll
    for (int i = 0; i < 6; i++) {
        int D = i * 4096 + wave * 1024 + lane * 16;
        int n = D >> 6, kb2 = D & 63;
        wOff[i] = (long)n * 2048 + (kb2 ^ ((n & 3) << 4));
        wLoff[i] = i * 4096 + wave * 1024;
    }
    long xOff[2]; int xLoff[2];
    #pragma unroll
    for (int i = 0; i < 2; i++) {
        int D = wave * 2048 + i * 1024 + lane * 16;
        int xr = D >> 7, xcb = D & 127;
        xOff[i] = (long)xr * 4096 + (xcb ^ ((xr & 7) << 4));
        xLoff[i] = wave * 2048 + i * 1024;
    }
    const char* xb = (const char*)x + row0 * 4096;
    const char* wb = (const char*)Wt;

    f32x4 acc[4][6] = {};

    {
        #pragma unroll
        for (int i = 0; i < 6; i++) gload16(wb + wOff[i], &wsm[0][0] + wLoff[i]);
        #pragma unroll
        for (int i = 0; i < 2; i++) gload16(xb + xOff[i], &xsm[0][0] + xLoff[i]);
    }
    asm volatile("s_waitcnt vmcnt(0)" ::: "memory");
    __builtin_amdgcn_s_barrier();

    const int asw = (lr & 7) << 4;
    const int bsw = (lr & 3) << 4;
    #pragma unroll 1
    for (int s = 0; s < 32; s++) {
        const int bi = s & 1;
        if (s + 1 < 32) {
            const char* wsrc = wb + (long)(s + 1) * 64;
            const char* xsrc = xb + (long)(s + 1) * 128;
            #pragma unroll
            for (int i = 0; i < 6; i++) gload16(wsrc + wOff[i], &wsm[bi ^ 1][0] + wLoff[i]);
            #pragma unroll
            for (int i = 0; i < 2; i++) gload16(xsrc + xOff[i], &xsm[bi ^ 1][0] + xLoff[i]);
        }
        const char* xp = &xsm[bi][0];
        const char* wp = &wsm[bi][0];
        bf16x8 a[4];
        #pragma unroll
        for (int ar = 0; ar < 4; ar++) {
            const int rbase = (ar * 16 + lr) * 128;
            f32x4 lo = *reinterpret_cast<const f32x4*>(xp + rbase + ((g * 32) ^ asw));
            f32x4 hi4 = *reinterpret_cast<const f32x4*>(xp + rbase + ((g * 32 + 16) ^ asw));
            uint4 u;
            u.x = pkbf(lo[0], lo[1]); u.y = pkbf(lo[2], lo[3]);
            u.z = pkbf(hi4[0], hi4[1]); u.w = pkbf(hi4[2], hi4[3]);
            a[ar] = __builtin_bit_cast(bf16x8, u);
        }
        #pragma unroll
        for (int nt = 0; nt < 6; nt++) {
            const int n = wave * 96 + nt * 16 + lr;
            bf16x8 bfr = *reinterpret_cast<const bf16x8*>(wp + n * 64 + ((g * 16) ^ bsw));
            #pragma unroll
            for (int ar = 0; ar < 4; ar++)
                acc[ar][nt] = __builtin_amdgcn_mfma_f32_16x16x32_bf16(a[ar], bfr, acc[ar][nt], 0, 0, 0);
        }
        asm volatile("s_waitcnt vmcnt(0)" ::: "memory");
        __builtin_amdgcn_s_barrier();
    }
    const float qscale = 0.08838834764831845f;
    bf16* outs[3] = {Q, K, V};
    #pragma unroll
    for (int nt = 0; nt < 6; nt++) {
        const int col = wave * 96 + nt * 16 + lr;
        const int w = col >> 7, d = col & 127;
        #pragma unroll
        for (int ar = 0; ar < 4; ar++)
            #pragma unroll
            for (int r = 0; r < 4; r++) {
                float val = acc[ar][nt][r];
                if (w == 0) val *= qscale;
                long row = row0 + ar * 16 + g * 4 + r;
                outs[w][row * 128 + d] = (bf16)val;
            }
    }
}

// ---- V transpose, tile-major: Vtt[b][t0/64][d][kv64] (each tile contiguous 16KB) ----
__global__ __launch_bounds__(256) void vtrans_kernel(const bf16* __restrict__ V,
                                                     bf16* __restrict__ Vtt) {
    __shared__ __align__(16) bf16 tile[64][136];
    const int tid = threadIdx.x;
    const int b = blockIdx.y;
    const int tt = blockIdx.x;
    const long ibase = ((long)b * TT + tt * 64) * 128;
    #pragma unroll
    for (int i = 0; i < 4; i++) {
        int slot = tid + 256 * i;
        int r = slot >> 4, c8 = (slot & 15) * 8;
        *reinterpret_cast<bf16x8*>(&tile[r][c8]) =
            *reinterpret_cast<const bf16x8*>(&V[ibase + r * 128 + c8]);
    }
    __syncthreads();
    #pragma unroll
    for (int i = 0; i < 4; i++) {
        int slot = tid + 256 * i;
        int d = slot >> 3, t8 = (slot & 7) * 8;
        bf16x8 v;
        #pragma unroll
        for (int j = 0; j < 8; j++) v[j] = tile[t8 + j][d];
        *reinterpret_cast<bf16x8*>(&Vtt[(((long)b * 64 + tt) * 128 + d) * 64 + t8]) = v;
    }
}

// ---- causal flash attention: 8 waves = 4 q-segs x 2 kv-streams, KVB=64 ----
// Block (v,b): phase1 qt=v, phase2 qt=31-v (128-row q-tiles). Stream h takes KVB=64
// tiles t == h (mod 2); nIt = qt+1 per phase, 33 per block -- uniform. Tiles staged
// contiguously (K row-major, Vtt tile-major) via global_load_lds, XOR-swizzled
// (rule #21), double-buffered, shared by the 4 waves of each stream. Streams merge
// (m,l,O) through LDS (reusing kv buffers) at phase end.
__global__ __launch_bounds__(512, 2) void attn_kernel(const bf16* __restrict__ Q,
                                                      const bf16* __restrict__ K,
                                                      const bf16* __restrict__ Vtt,
                                                      float* __restrict__ out) {
    __shared__ __align__(1024) char smem[131072];
    const int tid = threadIdx.x;
    const int wave = tid >> 6, lane = tid & 63;
    const int c = lane & 31, hi = lane >> 5;
    const int qs = wave >> 1, h = wave & 1;
    const int kswz = ((c & 7) << 4) ^ (((c >> 3) & 1) << 7);
    const int vswz = (c & 7) << 4;
    const int v = blockIdx.x >> 3, b = blockIdx.x & 7;   // batch pinned to XCD
    const long base = (long)b * TT * 128;
    const char* Kb = (const char*)(K + base);
    const char* Vb = (const char*)Vtt + (long)b * 64 * 16384;
    char* kB[2] = { smem + h * 32768, smem + h * 32768 + 16384 };
    char* vB[2] = { smem + 65536 + h * 32768, smem + 65536 + h * 32768 + 16384 };
    float* ml = (float*)(smem + 65536);                  // merge scalars (reused post-compute)

    long kOff[4], vOff[4]; int lOff[4];
    #pragma unroll
    for (int i = 0; i < 4; i++) {
        int D = qs * 4096 + i * 1024 + lane * 16;        // linear dest byte in 16KB tile
        int kr = D >> 8, kcb = D & 255;                  // K rows 256B
        kOff[i] = kr * 256 + (kcb ^ (((kr & 7) << 4) ^ (((kr >> 3) & 1) << 7)));
        int vr = D >> 7, vcb = D & 127;                  // V^T rows 128B
        vOff[i] = vr * 128 + (vcb ^ ((vr & 7) << 4));
        lOff[i] = qs * 4096 + i * 1024;
    }

    #pragma unroll 1
    for (int ph = 0; ph < 2; ph++) {
        const int qt = ph ? 31 - v : v;
        const int ntile = 2 * qt + 2;                    // KVB=64 tiles to diag
        const int nIt = qt + 1;
        const int q0w = qt * 128 + qs * 32;
        const int qa = q0w + c;

        bf16x8 qf[8];
        #pragma unroll
        for (int dw = 0; dw < 8; dw++)
            qf[dw] = *reinterpret_cast<const bf16x8*>(&Q[base + (long)qa * 128 + dw * 16 + hi * 8]);

        f32x16 O[4] = {};
        float m = -__builtin_inff(), l = 0.f;

        {   // prologue: stream h stages tile h -> buf0
            const char* Ks = Kb + (long)h * 16384;
            const char* Vs = Vb + (long)h * 16384;
            #pragma unroll
            for (int i = 0; i < 4; i++) {
                gload16(Ks + kOff[i], kB[0] + lOff[i]);
                gload16(Vs + vOff[i], vB[0] + lOff[i]);
            }
        }
        asm volatile("s_waitcnt vmcnt(0)" ::: "memory");
        __builtin_amdgcn_s_barrier();

        #pragma unroll 1
        for (int it = 0; it < nIt; it++) {
            const int bi = it & 1;
            const int t = h + 2 * it;
            if (t + 2 < ntile) {                         // issue next stage (overlaps compute)
                const char* Ks = Kb + (long)(t + 2) * 16384;
                const char* Vs = Vb + (long)(t + 2) * 16384;
                #pragma unroll
                for (int i = 0; i < 4; i++) {
                    gload16(Ks + kOff[i], kB[bi ^ 1] + lOff[i]);
                    gload16(Vs + vOff[i], vB[bi ^ 1] + lOff[i]);
                }
            }
            const int kv0 = t * 64;
            if (kv0 <= q0w + 31) {                       // wave has unmasked work
                const char* kb = kB[bi];
                const char* vb = vB[bi];
                f32x16 S0 = {}, S1 = {};
                #pragma unroll
                for (int dw = 0; dw < 8; dw++) {         // S^T = K Q^T (2 kv subtiles)
                    bf16x8 k0 = *reinterpret_cast<const bf16x8*>(
                        kb + c * 256 + ((dw * 32 + hi * 16) ^ kswz));
                    S0 = __builtin_amdgcn_mfma_f32_32x32x16_bf16(k0, qf[dw], S0, 0, 0, 0);
                    bf16x8 k1 = *reinterpret_cast<const bf16x8*>(
                        kb + 8192 + c * 256 + ((dw * 32 + hi * 16) ^ kswz));
                    S1 = __builtin_amdgcn_mfma_f32_32x32x16_bf16(k1, qf[dw], S1, 0, 0, 0);
                }
                if (kv0 + 63 > q0w) {                    // causal mask near diagonal
                    #pragma unroll
                    for (int i = 0; i < 16; i++) {
                        int kvr = kv0 + (i & 3) + 8 * (i >> 2) + 4 * hi;
                        if (kvr > qa)      S0[i] = -__builtin_inff();
                        if (kvr + 32 > qa) S1[i] = -__builtin_inff();
                    }
                }
                float t8[8];
                #pragma unroll
                for (int i = 0; i < 8; i++)
                    t8[i] = fmaxf(fmaxf(S0[i], S0[i + 8]), fmaxf(S1[i], S1[i + 8]));
                float t4a = fmaxf(t8[0], t8[4]), t4b = fmaxf(t8[1], t8[5]);
                float t4c = fmaxf(t8[2], t8[6]), t4d = fmaxf(t8[3], t8[7]);
                float pm = fmaxf(fmaxf(t4a, t4b), fmaxf(t4c, t4d));
                pm = fmaxf(pm, __shfl_xor(pm, 32, 64));
                if (!__all(pm - m <= 8.0f)) {            // defer-max
                    float mn = fmaxf(m, pm);
                    float fr = __expf(m - mn);
                    #pragma unroll
                    for (int dt = 0; dt < 4; dt++) O[dt] = O[dt] * fr;
                    l *= fr;
                    m = mn;
                }
                #pragma unroll
                for (int i = 0; i < 16; i++) {
                    S0[i] = __expf(S0[i] - m);
                    S1[i] = __expf(S1[i] - m);
                }
                float s8[8];
                #pragma unroll
                for (int i = 0; i < 8; i++)
                    s8[i] = (S0[i] + S0[i + 8]) + (S1[i] + S1[i + 8]);
                l += ((s8[0] + s8[4]) + (s8[1] + s8[5])) + ((s8[2] + s8[6]) + (s8[3] + s8[7]));

                bf16x8 pf[4];                            // P -> B-frags (pack + half-exchange)
                #pragma unroll
                for (int st = 0; st < 2; st++) {
                    #pragma unroll
                    for (int wl = 0; wl < 2; wl++) {
                        const int i0 = 8 * wl;
                        unsigned L0, L1, H0, H1;
                        if (st == 0) {
                            L0 = pkbf(S0[i0 + 0], S0[i0 + 1]); L1 = pkbf(S0[i0 + 2], S0[i0 + 3]);
                            H0 = pkbf(S0[i0 + 4], S0[i0 + 5]); H1 = pkbf(S0[i0 + 6], S0[i0 + 7]);
                        } else {
                            L0 = pkbf(S1[i0 + 0], S1[i0 + 1]); L1 = pkbf(S1[i0 + 2], S1[i0 + 3]);
                            H0 = pkbf(S1[i0 + 4], S1[i0 + 5]); H1 = pkbf(S1[i0 + 6], S1[i0 + 7]);
                        }
                        unsigned XL0 = __shfl_xor((int)L0, 32, 64);
                        unsigned XL1 = __shfl_xor((int)L1, 32, 64);
                        unsigned XH0 = __shfl_xor((int)H0, 32, 64);
                        unsigned XH1 = __shfl_xor((int)H1, 32, 64);
                        uint4 f;
                        f.x = hi ? XH0 : L0;
                        f.y = hi ? XH1 : L1;
                        f.z = hi ? H0  : XL0;
                        f.w = hi ? H1  : XL1;
                        pf[st * 2 + wl] = __builtin_bit_cast(bf16x8, f);
                    }
                }
                #pragma unroll
                for (int w4 = 0; w4 < 4; w4++)           // O^T += V^T P
                    #pragma unroll
                    for (int dt = 0; dt < 4; dt++) {
                        bf16x8 vf = *reinterpret_cast<const bf16x8*>(
                            vb + (dt * 32 + c) * 128 + ((w4 * 32 + hi * 16) ^ vswz));
                        O[dt] = __builtin_amdgcn_mfma_f32_32x32x16_bf16(vf, pf[w4], O[dt], 0, 0, 0);
                    }
            }
            asm volatile("s_waitcnt vmcnt(0)" ::: "memory");
            __builtin_amdgcn_s_barrier();
        }

        l += __shfl_xor(l, 32, 64);                      // combine partner kv-row halves

        if (h == 1) {                                    // stream 1 publishes partials
            char* om = smem + qs * 16384;
            #pragma unroll
            for (int dt = 0; dt < 4; dt++)
                #pragma unroll
                for (int g = 0; g < 4; g++) {
                    float4 w4v = { O[dt][4 * g + 0], O[dt][4 * g + 1],
                                   O[dt][4 * g + 2], O[dt][4 * g + 3] };
                    *reinterpret_cast<float4*>(
                        om + c * 512 + ((dt * 128 + g * 32 + hi * 16) ^ ((c & 7) << 4))) = w4v;
                }
            if (hi == 0) { ml[qs * 64 + c] = m; ml[qs * 64 + 32 + c] = l; }
        }
        __syncthreads();
        if (h == 0) {                                    // stream 0 merges + writes out
            float m1 = ml[qs * 64 + c], l1 = ml[qs * 64 + 32 + c];
            float mx = fmaxf(m, m1);
            float f0 = __expf(m - mx), f1 = __expf(m1 - mx);
            float linv = 1.0f / (l * f0 + l1 * f1);
            const char* om = smem + qs * 16384;
            #pragma unroll
            for (int dt = 0; dt < 4; dt++)
                #pragma unroll
                for (int g = 0; g < 4; g++) {
                    float4 o1 = *reinterpret_cast<const float4*>(
                        om + c * 512 + ((dt * 128 + g * 32 + hi * 16) ^ ((c & 7) << 4)));
                    float4 r;
                    r.x = (O[dt][4 * g + 0] * f0 + o1.x * f1) * linv;
                    r.y = (O[dt][4 * g + 1] * f0 + o1.y * f1) * linv;
                    r.z = (O[dt][4 * g + 2] * f0 + o1.z * f1) * linv;
                    r.w = (O[dt][4 * g + 3] * f0 + o1.w * f1) * linv;
                    *reinterpret_cast<float4*>(
                        &out[base + (long)qa * 128 + dt * 32 + 8 * g + 4 * hi]) = r;
                }
        }
        __syncthreads();                                 // LDS safe before next phase stages
    }
}

extern "C" void kernel_launch(void* const* d_in, const int* in_sizes, int n_in,
                              void* d_out, int out_size, void* d_ws, size_t ws_size,
                              hipStream_t stream) {
    const float* x  = (const float*)d_in[0];
    const float* Wq = (const float*)d_in[1];
    const float* Wk = (const float*)d_in[2];
    const float* Wv = (const float*)d_in[3];
    float* out = (float*)d_out;
    bf16* Q   = (bf16*)d_ws;                      // [32768][128]
    bf16* K   = Q   + (size_t)32768 * 128;
    bf16* V   = K   + (size_t)32768 * 128;
    bf16* Wt  = V   + (size_t)32768 * 128;        // [3][128][1024]
    bf16* Vtt = Wt  + (size_t)3 * 128 * 1024;     // [8][64][128][64] tile-major
    wt_kernel<<<96, 256, 0, stream>>>(Wq, Wk, Wv, Wt);
    qkv_kernel<<<512, 256, 0, stream>>>(x, Wt, Q, K, V);
    vtrans_kernel<<<dim3(64, 8), 256, 0, stream>>>(V, Vtt);
    attn_kernel<<<256, 512, 0, stream>>>(Q, K, Vtt, out);
}

// Round 7
// 142.704 us; speedup vs baseline: 1.2685x; 1.2685x over previous
//
#include <hip/hip_runtime.h>
#include <hip/hip_bf16.h>

#define TB 8
#define TT 4096
#define TC 1024
#define THS 128

typedef __bf16 bf16;
typedef __attribute__((ext_vector_type(8))) __bf16 bf16x8;
typedef __attribute__((ext_vector_type(2))) __bf16 bf16x2;
typedef __attribute__((ext_vector_type(4))) float f32x4;
typedef __attribute__((ext_vector_type(16))) float f32x16;

__device__ __forceinline__ unsigned pkbf(float a, float b) {
    bf16x2 t = { (bf16)a, (bf16)b };
    return __builtin_bit_cast(unsigned, t);
}

__device__ __forceinline__ void gload16(const void* g, void* l) {
    __builtin_amdgcn_global_load_lds(
        (const __attribute__((address_space(1))) void*)g,
        (__attribute__((address_space(3))) void*)l, 16, 0, 0);
}

// ---- W cast+transpose via LDS tile: Wt[w][n][k] = bf16(W_w[k][n]) ----
__global__ __launch_bounds__(256) void wt_kernel(const float* __restrict__ Wq,
                                                 const float* __restrict__ Wk,
                                                 const float* __restrict__ Wv,
                                                 bf16* __restrict__ Wt) {
    __shared__ float tile[64][65];
    const int tid = threadIdx.x;
    const int idx = blockIdx.x;                  // 96 blocks: w*32 + kt*2 + ntb
    const int w = idx >> 5;
    const int kt = (idx & 31) >> 1, ntb = idx & 1;
    const int k0 = kt * 64, n0 = ntb * 64;
    const float* W = (w == 0) ? Wq : (w == 1) ? Wk : Wv;
    #pragma unroll
    for (int i = 0; i < 4; i++) {
        int r = (tid >> 4) + i * 16;
        int c4 = (tid & 15) * 4;
        float4 x4 = *reinterpret_cast<const float4*>(&W[(long)(k0 + r) * 128 + n0 + c4]);
        tile[r][c4 + 0] = x4.x; tile[r][c4 + 1] = x4.y;
        tile[r][c4 + 2] = x4.z; tile[r][c4 + 3] = x4.w;
    }
    __syncthreads();
    const int n = tid >> 2, kk = (tid & 3) * 16;
    bf16 o[16];
    #pragma unroll
    for (int j = 0; j < 16; j++) o[j] = (bf16)tile[kk + j][n];
    bf16* dst = &Wt[(long)((w << 7) + n0 + n) * 1024 + k0 + kk];
    *reinterpret_cast<bf16x8*>(dst)     = *reinterpret_cast<bf16x8*>(&o[0]);
    *reinterpret_cast<bf16x8*>(dst + 8) = *reinterpret_cast<bf16x8*>(&o[8]);
}

// ---- fused QKV projection (unchanged) ----
__global__ __launch_bounds__(256, 2) void qkv_kernel(const float* __restrict__ x,
                                                     const bf16* __restrict__ Wt,
                                                     bf16* __restrict__ Q,
                                                     bf16* __restrict__ K,
                                                     bf16* __restrict__ V) {
    __shared__ __align__(1024) char wsm[2][24576];
    __shared__ __align__(1024) char xsm[2][8192];
    const int tid = threadIdx.x;
    const int wave = tid >> 6, lane = tid & 63;
    const int lr = lane & 15, g = lane >> 4;
    const long row0 = (long)blockIdx.x * 64;

    long wOff[6]; int wLoff[6];
    #pragma unroll
    for (int i = 0; i < 6; i++) {
        int D = i * 4096 + wave * 1024 + lane * 16;
        int n = D >> 6, kb2 = D & 63;
        wOff[i] = (long)n * 2048 + (kb2 ^ ((n & 3) << 4));
        wLoff[i] = i * 4096 + wave * 1024;
    }
    long xOff[2]; int xLoff[2];
    #pragma unroll
    for (int i = 0; i < 2; i++) {
        int D = wave * 2048 + i * 1024 + lane * 16;
        int xr = D >> 7, xcb = D & 127;
        xOff[i] = (long)xr * 4096 + (xcb ^ ((xr & 7) << 4));
        xLoff[i] = wave * 2048 + i * 1024;
    }
    const char* xb = (const char*)x + row0 * 4096;
    const char* wb = (const char*)Wt;

    f32x4 acc[4][6] = {};

    {
        #pragma unroll
        for (int i = 0; i < 6; i++) gload16(wb + wOff[i], &wsm[0][0] + wLoff[i]);
        #pragma unroll
        for (int i = 0; i < 2; i++) gload16(xb + xOff[i], &xsm[0][0] + xLoff[i]);
    }
    asm volatile("s_waitcnt vmcnt(0)" ::: "memory");
    __builtin_amdgcn_s_barrier();

    const int asw = (lr & 7) << 4;
    const int bsw = (lr & 3) << 4;
    #pragma unroll 1
    for (int s = 0; s < 32; s++) {
        const int bi = s & 1;
        if (s + 1 < 32) {
            const char* wsrc = wb + (long)(s + 1) * 64;
            const char* xsrc = xb + (long)(s + 1) * 128;
            #pragma unroll
            for (int i = 0; i < 6; i++) gload16(wsrc + wOff[i], &wsm[bi ^ 1][0] + wLoff[i]);
            #pragma unroll
            for (int i = 0; i < 2; i++) gload16(xsrc + xOff[i], &xsm[bi ^ 1][0] + xLoff[i]);
        }
        const char* xp = &xsm[bi][0];
        const char* wp = &wsm[bi][0];
        bf16x8 a[4];
        #pragma unroll
        for (int ar = 0; ar < 4; ar++) {
            const int rbase = (ar * 16 + lr) * 128;
            f32x4 lo = *reinterpret_cast<const f32x4*>(xp + rbase + ((g * 32) ^ asw));
            f32x4 hi4 = *reinterpret_cast<const f32x4*>(xp + rbase + ((g * 32 + 16) ^ asw));
            uint4 u;
            u.x = pkbf(lo[0], lo[1]); u.y = pkbf(lo[2], lo[3]);
            u.z = pkbf(hi4[0], hi4[1]); u.w = pkbf(hi4[2], hi4[3]);
            a[ar] = __builtin_bit_cast(bf16x8, u);
        }
        #pragma unroll
        for (int nt = 0; nt < 6; nt++) {
            const int n = wave * 96 + nt * 16 + lr;
            bf16x8 bfr = *reinterpret_cast<const bf16x8*>(wp + n * 64 + ((g * 16) ^ bsw));
            #pragma unroll
            for (int ar = 0; ar < 4; ar++)
                acc[ar][nt] = __builtin_amdgcn_mfma_f32_16x16x32_bf16(a[ar], bfr, acc[ar][nt], 0, 0, 0);
        }
        asm volatile("s_waitcnt vmcnt(0)" ::: "memory");
        __builtin_amdgcn_s_barrier();
    }
    const float qscale = 0.08838834764831845f;
    bf16* outs[3] = {Q, K, V};
    #pragma unroll
    for (int nt = 0; nt < 6; nt++) {
        const int col = wave * 96 + nt * 16 + lr;
        const int w = col >> 7, d = col & 127;
        #pragma unroll
        for (int ar = 0; ar < 4; ar++)
            #pragma unroll
            for (int r = 0; r < 4; r++) {
                float val = acc[ar][nt][r];
                if (w == 0) val *= qscale;
                long row = row0 + ar * 16 + g * 4 + r;
                outs[w][row * 128 + d] = (bf16)val;
            }
    }
}

// ---- V transpose, tile-major: Vtt[b][t64][d][kv64] (each tile contiguous 16KB) ----
__global__ __launch_bounds__(256) void vtrans_kernel(const bf16* __restrict__ V,
                                                     bf16* __restrict__ Vtt) {
    __shared__ __align__(16) bf16 tile[64][136];
    const int tid = threadIdx.x;
    const int b = blockIdx.y;
    const int tt = blockIdx.x;
    const long ibase = ((long)b * TT + tt * 64) * 128;
    #pragma unroll
    for (int i = 0; i < 4; i++) {
        int slot = tid + 256 * i;
        int r = slot >> 4, c8 = (slot & 15) * 8;
        *reinterpret_cast<bf16x8*>(&tile[r][c8]) =
            *reinterpret_cast<const bf16x8*>(&V[ibase + r * 128 + c8]);
    }
    __syncthreads();
    #pragma unroll
    for (int i = 0; i < 4; i++) {
        int slot = tid + 256 * i;
        int d = slot >> 3, t8 = (slot & 7) * 8;
        bf16x8 v;
        #pragma unroll
        for (int j = 0; j < 8; j++) v[j] = tile[t8 + j][d];
        *reinterpret_cast<bf16x8*>(&Vtt[(((long)b * 64 + tt) * 128 + d) * 64 + t8]) = v;
    }
}

// ---- causal flash attention, flash-decoding items + in-block kv-streams ----
// Item (qt in [0,32), h in {0,1}): q rows [128qt, 128qt+128), KVB=64 tiles
// gt in [h*(qt+1), (h+1)*(qt+1)). Block (v,b): phase1 item u=v, phase2 u=63-v
// -> per-block iterations ceil((qt_a+1)/2)+ceil((qt_b+1)/2) = 17, uniform.
// 8 waves = 4 q-segs x 2 streams (stream sid takes local tiles == sid mod 2).
// Streams merge in-LDS; item partial (O,m,l) -> pO/pML; external merge kernel.
__global__ __launch_bounds__(512, 2) void attn_kernel(const bf16* __restrict__ Q,
                                                      const bf16* __restrict__ K,
                                                      const bf16* __restrict__ Vtt,
                                                      float* __restrict__ pO,
                                                      float* __restrict__ pML) {
    __shared__ __align__(1024) char smem[131072];
    const int tid = threadIdx.x;
    const int wave = tid >> 6, lane = tid & 63;
    const int c = lane & 31, hi = lane >> 5;
    const int qs = wave >> 1, sid = wave & 1;
    const int kswz = ((c & 7) << 4) ^ (((c >> 3) & 1) << 7);
    const int vswz = (c & 7) << 4;
    const int v = blockIdx.x >> 3, b = blockIdx.x & 7;   // batch pinned to XCD
    const long base = (long)b * TT * 128;
    const char* Kb = (const char*)(K + base);
    const char* Vb = (const char*)Vtt + (long)b * 64 * 16384;
    char* kB[2] = { smem + sid * 32768, smem + sid * 32768 + 16384 };
    char* vB[2] = { smem + 65536 + sid * 32768, smem + 65536 + sid * 32768 + 16384 };
    float* ml = (float*)(smem + 65536);                  // merge scalars (reused post-compute)

    long kOff[4], vOff[4]; int lOff[4];
    #pragma unroll
    for (int i = 0; i < 4; i++) {
        int D = qs * 4096 + i * 1024 + lane * 16;        // linear dest byte in 16KB tile
        int kr = D >> 8, kcb = D & 255;                  // K rows 256B
        kOff[i] = kr * 256 + (kcb ^ (((kr & 7) << 4) ^ (((kr >> 3) & 1) << 7)));
        int vr = D >> 7, vcb = D & 127;                  // V^T rows 128B
        vOff[i] = vr * 128 + (vcb ^ ((vr & 7) << 4));
        lOff[i] = qs * 4096 + i * 1024;
    }

    #pragma unroll 1
    for (int ph = 0; ph < 2; ph++) {
        const int u = ph ? 63 - v : v;
        const int qt = u >> 1, h = u & 1;
        const int ntI = qt + 1;                          // tiles in this item
        const int nIt = (ntI + 1) >> 1;                  // iterations per stream
        const int tb = h * ntI;                          // first global tile
        const int q0w = qt * 128 + qs * 32;
        const int qa = q0w + c;

        bf16x8 qf[8];
        #pragma unroll
        for (int dw = 0; dw < 8; dw++)
            qf[dw] = *reinterpret_cast<const bf16x8*>(&Q[base + (long)qa * 128 + dw * 16 + hi * 8]);

        f32x16 O[4] = {};
        float m = -__builtin_inff(), l = 0.f;

        if (sid < ntI) {                                 // prologue: stage tile tb+sid -> buf0
            const char* Ks = Kb + (long)(tb + sid) * 16384;
            const char* Vs = Vb + (long)(tb + sid) * 16384;
            #pragma unroll
            for (int i = 0; i < 4; i++) {
                gload16(Ks + kOff[i], kB[0] + lOff[i]);
                gload16(Vs + vOff[i], vB[0] + lOff[i]);
            }
        }
        asm volatile("s_waitcnt vmcnt(0)" ::: "memory");
        __builtin_amdgcn_s_barrier();

        #pragma unroll 1
        for (int it = 0; it < nIt; it++) {
            const int bi = it & 1;
            const int lt = sid + 2 * it;
            if (lt + 2 < ntI) {                          // issue next stage (overlaps compute)
                const char* Ks = Kb + (long)(tb + lt + 2) * 16384;
                const char* Vs = Vb + (long)(tb + lt + 2) * 16384;
                #pragma unroll
                for (int i = 0; i < 4; i++) {
                    gload16(Ks + kOff[i], kB[bi ^ 1] + lOff[i]);
                    gload16(Vs + vOff[i], vB[bi ^ 1] + lOff[i]);
                }
            }
            const int kv0 = (tb + lt) * 64;
            if (lt < ntI && kv0 <= q0w + 31) {           // wave has unmasked work
                const char* kb = kB[bi];
                const char* vb = vB[bi];
                f32x16 S0 = {}, S1 = {};
                __builtin_amdgcn_s_setprio(1);
                #pragma unroll
                for (int dw = 0; dw < 8; dw++) {         // S^T = K Q^T (2 kv subtiles)
                    bf16x8 k0 = *reinterpret_cast<const bf16x8*>(
                        kb + c * 256 + ((dw * 32 + hi * 16) ^ kswz));
                    S0 = __builtin_amdgcn_mfma_f32_32x32x16_bf16(k0, qf[dw], S0, 0, 0, 0);
                    bf16x8 k1 = *reinterpret_cast<const bf16x8*>(
                        kb + 8192 + c * 256 + ((dw * 32 + hi * 16) ^ kswz));
                    S1 = __builtin_amdgcn_mfma_f32_32x32x16_bf16(k1, qf[dw], S1, 0, 0, 0);
                }
                __builtin_amdgcn_s_setprio(0);
                if (kv0 + 63 > q0w) {                    // causal mask near diagonal
                    #pragma unroll
                    for (int i = 0; i < 16; i++) {
                        int kvr = kv0 + (i & 3) + 8 * (i >> 2) + 4 * hi;
                        if (kvr > qa)      S0[i] = -__builtin_inff();
                        if (kvr + 32 > qa) S1[i] = -__builtin_inff();
                    }
                }
                float t8[8];
                #pragma unroll
                for (int i = 0; i < 8; i++)
                    t8[i] = fmaxf(fmaxf(S0[i], S0[i + 8]), fmaxf(S1[i], S1[i + 8]));
                float t4a = fmaxf(t8[0], t8[4]), t4b = fmaxf(t8[1], t8[5]);
                float t4c = fmaxf(t8[2], t8[6]), t4d = fmaxf(t8[3], t8[7]);
                float pm = fmaxf(fmaxf(t4a, t4b), fmaxf(t4c, t4d));
                pm = fmaxf(pm, __shfl_xor(pm, 32, 64));
                if (!__all(pm - m <= 8.0f)) {            // defer-max
                    float mn = fmaxf(m, pm);
                    float fr = __expf(m - mn);
                    #pragma unroll
                    for (int dt = 0; dt < 4; dt++) O[dt] = O[dt] * fr;
                    l *= fr;
                    m = mn;
                }
                #pragma unroll
                for (int i = 0; i < 16; i++) {
                    S0[i] = __expf(S0[i] - m);
                    S1[i] = __expf(S1[i] - m);
                }
                float s8[8];
                #pragma unroll
                for (int i = 0; i < 8; i++)
                    s8[i] = (S0[i] + S0[i + 8]) + (S1[i] + S1[i + 8]);
                l += ((s8[0] + s8[4]) + (s8[1] + s8[5])) + ((s8[2] + s8[6]) + (s8[3] + s8[7]));

                bf16x8 pf[4];                            // P -> B-frags (pack + half-exchange)
                #pragma unroll
                for (int st = 0; st < 2; st++) {
                    #pragma unroll
                    for (int wl = 0; wl < 2; wl++) {
                        const int i0 = 8 * wl;
                        unsigned L0, L1, H0, H1;
                        if (st == 0) {
                            L0 = pkbf(S0[i0 + 0], S0[i0 + 1]); L1 = pkbf(S0[i0 + 2], S0[i0 + 3]);
                            H0 = pkbf(S0[i0 + 4], S0[i0 + 5]); H1 = pkbf(S0[i0 + 6], S0[i0 + 7]);
                        } else {
                            L0 = pkbf(S1[i0 + 0], S1[i0 + 1]); L1 = pkbf(S1[i0 + 2], S1[i0 + 3]);
                            H0 = pkbf(S1[i0 + 4], S1[i0 + 5]); H1 = pkbf(S1[i0 + 6], S1[i0 + 7]);
                        }
                        unsigned XL0 = __shfl_xor((int)L0, 32, 64);
                        unsigned XL1 = __shfl_xor((int)L1, 32, 64);
                        unsigned XH0 = __shfl_xor((int)H0, 32, 64);
                        unsigned XH1 = __shfl_xor((int)H1, 32, 64);
                        uint4 f;
                        f.x = hi ? XH0 : L0;
                        f.y = hi ? XH1 : L1;
                        f.z = hi ? H0  : XL0;
                        f.w = hi ? H1  : XL1;
                        pf[st * 2 + wl] = __builtin_bit_cast(bf16x8, f);
                    }
                }
                __builtin_amdgcn_s_setprio(1);
                #pragma unroll
                for (int w4 = 0; w4 < 4; w4++)           // O^T += V^T P
                    #pragma unroll
                    for (int dt = 0; dt < 4; dt++) {
                        bf16x8 vf = *reinterpret_cast<const bf16x8*>(
                            vb + (dt * 32 + c) * 128 + ((w4 * 32 + hi * 16) ^ vswz));
                        O[dt] = __builtin_amdgcn_mfma_f32_32x32x16_bf16(vf, pf[w4], O[dt], 0, 0, 0);
                    }
                __builtin_amdgcn_s_setprio(0);
            }
            asm volatile("s_waitcnt vmcnt(0)" ::: "memory");
            __builtin_amdgcn_s_barrier();
        }

        l += __shfl_xor(l, 32, 64);                      // combine partner kv-row halves

        if (sid == 1) {                                  // stream 1 publishes partials
            char* om = smem + qs * 16384;
            #pragma unroll
            for (int dt = 0; dt < 4; dt++)
                #pragma unroll
                for (int g = 0; g < 4; g++) {
                    float4 w4v = { O[dt][4 * g + 0], O[dt][4 * g + 1],
                                   O[dt][4 * g + 2], O[dt][4 * g + 3] };
                    *reinterpret_cast<float4*>(
                        om + c * 512 + ((dt * 128 + g * 32 + hi * 16) ^ ((c & 7) << 4))) = w4v;
                }
            if (hi == 0) { ml[qs * 64 + c] = m; ml[qs * 64 + 32 + c] = l; }
        }
        __syncthreads();
        if (sid == 0) {                                  // stream 0 merges streams, writes partial
            float m1 = ml[qs * 64 + c], l1 = ml[qs * 64 + 32 + c];
            float mx = fmaxf(fmaxf(m, m1), -1.0e30f);    // clamp: empty item stays NaN-free
            float f0 = __expf(m - mx), f1 = __expf(m1 - mx);
            float lm = l * f0 + l1 * f1;
            const int pidx = (b * 32 + qt) * 2 + h;
            const int row = qs * 32 + c;
            if (hi == 0) {
                pML[(long)pidx * 256 + row] = mx;
                pML[(long)pidx * 256 + 128 + row] = lm;
            }
            float* po = pO + (long)pidx * 16384 + (long)row * 128;
            const char* om = smem + qs * 16384;
            #pragma unroll
            for (int dt = 0; dt < 4; dt++)
                #pragma unroll
                for (int g = 0; g < 4; g++) {
                    float4 o1 = *reinterpret_cast<const float4*>(
                        om + c * 512 + ((dt * 128 + g * 32 + hi * 16) ^ ((c & 7) << 4)));
                    float4 r;
                    r.x = O[dt][4 * g + 0] * f0 + o1.x * f1;
                    r.y = O[dt][4 * g + 1] * f0 + o1.y * f1;
                    r.z = O[dt][4 * g + 2] * f0 + o1.z * f1;
                    r.w = O[dt][4 * g + 3] * f0 + o1.w * f1;
                    *reinterpret_cast<float4*>(&po[dt * 32 + 8 * g + 4 * hi]) = r;
                }
        }
        __syncthreads();                                 // LDS safe before next phase stages
    }
}

// ---- merge the two kv-halves of each q-tile (coalesced out writes) ----
__global__ __launch_bounds__(256) void merge_kernel(const float* __restrict__ pO,
                                                    const float* __restrict__ pML,
                                                    float* __restrict__ out) {
    const int qt = blockIdx.x >> 3, b = blockIdx.x & 7;
    const int tid = threadIdx.x;
    const int sub = tid >> 5;                            // 8 rows per pass
    const int c4 = (tid & 31) * 4;
    const long pidx0 = (long)(b * 32 + qt) * 2;
    const float* mlp = pML + pidx0 * 256;
    #pragma unroll 1
    for (int pass = 0; pass < 16; pass++) {
        const int r = pass * 8 + sub;
        float m0 = mlp[r],       l0 = mlp[128 + r];
        float m1 = mlp[256 + r], l1 = mlp[384 + r];
        float mx = fmaxf(m0, m1);
        float f0 = __expf(m0 - mx), f1 = __expf(m1 - mx);
        float linv = 1.0f / (l0 * f0 + l1 * f1);
        const float* o0 = pO + pidx0 * 16384 + (long)r * 128 + c4;
        const float* o1 = o0 + 16384;
        float4 a = *reinterpret_cast<const float4*>(o0);
        float4 d = *reinterpret_cast<const float4*>(o1);
        float4 rr;
        rr.x = (a.x * f0 + d.x * f1) * linv;
        rr.y = (a.y * f0 + d.y * f1) * linv;
        rr.z = (a.z * f0 + d.z * f1) * linv;
        rr.w = (a.w * f0 + d.w * f1) * linv;
        *reinterpret_cast<float4*>(&out[((long)b * TT + (long)qt * 128 + r) * 128 + c4]) = rr;
    }
}

extern "C" void kernel_launch(void* const* d_in, const int* in_sizes, int n_in,
                              void* d_out, int out_size, void* d_ws, size_t ws_size,
                              hipStream_t stream) {
    const float* x  = (const float*)d_in[0];
    const float* Wq = (const float*)d_in[1];
    const float* Wk = (const float*)d_in[2];
    const float* Wv = (const float*)d_in[3];
    float* out = (float*)d_out;
    bf16* Q   = (bf16*)d_ws;                      // [32768][128]
    bf16* K   = Q   + (size_t)32768 * 128;
    bf16* V   = K   + (size_t)32768 * 128;
    bf16* Wt  = V   + (size_t)32768 * 128;        // [3][128][1024]
    bf16* Vtt = Wt  + (size_t)3 * 128 * 1024;     // [8][64][128][64] tile-major
    float* pO  = (float*)(Vtt + (size_t)8 * 64 * 128 * 64);  // [512][128][128]
    float* pML = pO + (size_t)512 * 16384;                   // [512][2][128]
    wt_kernel<<<96, 256, 0, stream>>>(Wq, Wk, Wv, Wt);
    qkv_kernel<<<512, 256, 0, stream>>>(x, Wt, Q, K, V);
    vtrans_kernel<<<dim3(64, 8), 256, 0, stream>>>(V, Vtt);
    attn_kernel<<<256, 512, 0, stream>>>(Q, K, Vtt, pO, pML);
    merge_kernel<<<256, 256, 0, stream>>>(pO, pML, out);
}

// Round 9
// 116.893 us; speedup vs baseline: 1.5486x; 1.2208x over previous
//
#include <hip/hip_runtime.h>
#include <hip/hip_bf16.h>

#define TB 8
#define TT 4096
#define TC 1024
#define THS 128

typedef __bf16 bf16;
typedef __attribute__((ext_vector_type(8))) __bf16 bf16x8;
typedef __attribute__((ext_vector_type(2))) __bf16 bf16x2;
typedef __attribute__((ext_vector_type(4))) float f32x4;
typedef __attribute__((ext_vector_type(16))) float f32x16;

__device__ __forceinline__ unsigned pkbf(float a, float b) {
    bf16x2 t = { (bf16)a, (bf16)b };
    return __builtin_bit_cast(unsigned, t);
}

__device__ __forceinline__ void gload16(const void* g, void* l) {
    __builtin_amdgcn_global_load_lds(
        (const __attribute__((address_space(1))) void*)g,
        (__attribute__((address_space(3))) void*)l, 16, 0, 0);
}

// ---- W cast+transpose via LDS tile: Wt[w][n][k] = bf16(W_w[k][n]) ----
__global__ __launch_bounds__(256) void wt_kernel(const float* __restrict__ Wq,
                                                 const float* __restrict__ Wk,
                                                 const float* __restrict__ Wv,
                                                 bf16* __restrict__ Wt) {
    __shared__ float tile[64][65];
    const int tid = threadIdx.x;
    const int idx = blockIdx.x;                  // 96 blocks: w*32 + kt*2 + ntb
    const int w = idx >> 5;
    const int kt = (idx & 31) >> 1, ntb = idx & 1;
    const int k0 = kt * 64, n0 = ntb * 64;
    const float* W = (w == 0) ? Wq : (w == 1) ? Wk : Wv;
    #pragma unroll
    for (int i = 0; i < 4; i++) {
        int r = (tid >> 4) + i * 16;
        int c4 = (tid & 15) * 4;
        float4 x4 = *reinterpret_cast<const float4*>(&W[(long)(k0 + r) * 128 + n0 + c4]);
        tile[r][c4 + 0] = x4.x; tile[r][c4 + 1] = x4.y;
        tile[r][c4 + 2] = x4.z; tile[r][c4 + 3] = x4.w;
    }
    __syncthreads();
    const int n = tid >> 2, kk = (tid & 3) * 16;
    bf16 o[16];
    #pragma unroll
    for (int j = 0; j < 16; j++) o[j] = (bf16)tile[kk + j][n];
    bf16* dst = &Wt[(long)((w << 7) + n0 + n) * 1024 + k0 + kk];
    *reinterpret_cast<bf16x8*>(dst)     = *reinterpret_cast<bf16x8*>(&o[0]);
    *reinterpret_cast<bf16x8*>(dst + 8) = *reinterpret_cast<bf16x8*>(&o[8]);
}

// ---- fused QKV projection (unchanged) ----
__global__ __launch_bounds__(256, 2) void qkv_kernel(const float* __restrict__ x,
                                                     const bf16* __restrict__ Wt,
                                                     bf16* __restrict__ Q,
                                                     bf16* __restrict__ K,
                                                     bf16* __restrict__ V) {
    __shared__ __align__(1024) char wsm[2][24576];
    __shared__ __align__(1024) char xsm[2][8192];
    const int tid = threadIdx.x;
    const int wave = tid >> 6, lane = tid & 63;
    const int lr = lane & 15, g = lane >> 4;
    const long row0 = (long)blockIdx.x * 64;

    long wOff[6]; int wLoff[6];
    #pragma unroll
    for (int i = 0; i < 6; i++) {
        int D = i * 4096 + wave * 1024 + lane * 16;
        int n = D >> 6, kb2 = D & 63;
        wOff[i] = (long)n * 2048 + (kb2 ^ ((n & 3) << 4));
        wLoff[i] = i * 4096 + wave * 1024;
    }
    long xOff[2]; int xLoff[2];
    #pragma unroll
    for (int i = 0; i < 2; i++) {
        int D = wave * 2048 + i * 1024 + lane * 16;
        int xr = D >> 7, xcb = D & 127;
        xOff[i] = (long)xr * 4096 + (xcb ^ ((xr & 7) << 4));
        xLoff[i] = wave * 2048 + i * 1024;
    }
    const char* xb = (const char*)x + row0 * 4096;
    const char* wb = (const char*)Wt;

    f32x4 acc[4][6] = {};

    {
        #pragma unroll
        for (int i = 0; i < 6; i++) gload16(wb + wOff[i], &wsm[0][0] + wLoff[i]);
        #pragma unroll
        for (int i = 0; i < 2; i++) gload16(xb + xOff[i], &xsm[0][0] + xLoff[i]);
    }
    asm volatile("s_waitcnt vmcnt(0)" ::: "memory");
    __builtin_amdgcn_s_barrier();

    const int asw = (lr & 7) << 4;
    const int bsw = (lr & 3) << 4;
    #pragma unroll 1
    for (int s = 0; s < 32; s++) {
        const int bi = s & 1;
        if (s + 1 < 32) {
            const char* wsrc = wb + (long)(s + 1) * 64;
            const char* xsrc = xb + (long)(s + 1) * 128;
            #pragma unroll
            for (int i = 0; i < 6; i++) gload16(wsrc + wOff[i], &wsm[bi ^ 1][0] + wLoff[i]);
            #pragma unroll
            for (int i = 0; i < 2; i++) gload16(xsrc + xOff[i], &xsm[bi ^ 1][0] + xLoff[i]);
        }
        const char* xp = &xsm[bi][0];
        const char* wp = &wsm[bi][0];
        bf16x8 a[4];
        #pragma unroll
        for (int ar = 0; ar < 4; ar++) {
            const int rbase = (ar * 16 + lr) * 128;
            f32x4 lo = *reinterpret_cast<const f32x4*>(xp + rbase + ((g * 32) ^ asw));
            f32x4 hi4 = *reinterpret_cast<const f32x4*>(xp + rbase + ((g * 32 + 16) ^ asw));
            uint4 u;
            u.x = pkbf(lo[0], lo[1]); u.y = pkbf(lo[2], lo[3]);
            u.z = pkbf(hi4[0], hi4[1]); u.w = pkbf(hi4[2], hi4[3]);
            a[ar] = __builtin_bit_cast(bf16x8, u);
        }
        #pragma unroll
        for (int nt = 0; nt < 6; nt++) {
            const int n = wave * 96 + nt * 16 + lr;
            bf16x8 bfr = *reinterpret_cast<const bf16x8*>(wp + n * 64 + ((g * 16) ^ bsw));
            #pragma unroll
            for (int ar = 0; ar < 4; ar++)
                acc[ar][nt] = __builtin_amdgcn_mfma_f32_16x16x32_bf16(a[ar], bfr, acc[ar][nt], 0, 0, 0);
        }
        asm volatile("s_waitcnt vmcnt(0)" ::: "memory");
        __builtin_amdgcn_s_barrier();
    }
    const float qscale = 0.08838834764831845f;
    bf16* outs[3] = {Q, K, V};
    #pragma unroll
    for (int nt = 0; nt < 6; nt++) {
        const int col = wave * 96 + nt * 16 + lr;
        const int w = col >> 7, d = col & 127;
        #pragma unroll
        for (int ar = 0; ar < 4; ar++)
            #pragma unroll
            for (int r = 0; r < 4; r++) {
                float val = acc[ar][nt][r];
                if (w == 0) val *= qscale;
                long row = row0 + ar * 16 + g * 4 + r;
                outs[w][row * 128 + d] = (bf16)val;
            }
    }
}

// ---- V transpose, tile-major: Vtt[b][t64][d][kv64] (each tile contiguous 16KB) ----
__global__ __launch_bounds__(256) void vtrans_kernel(const bf16* __restrict__ V,
                                                     bf16* __restrict__ Vtt) {
    __shared__ __align__(16) bf16 tile[64][136];
    const int tid = threadIdx.x;
    const int b = blockIdx.y;
    const int tt = blockIdx.x;
    const long ibase = ((long)b * TT + tt * 64) * 128;
    #pragma unroll
    for (int i = 0; i < 4; i++) {
        int slot = tid + 256 * i;
        int r = slot >> 4, c8 = (slot & 15) * 8;
        *reinterpret_cast<bf16x8*>(&tile[r][c8]) =
            *reinterpret_cast<const bf16x8*>(&V[ibase + r * 128 + c8]);
    }
    __syncthreads();
    #pragma unroll
    for (int i = 0; i < 4; i++) {
        int slot = tid + 256 * i;
        int d = slot >> 3, t8 = (slot & 7) * 8;
        bf16x8 v;
        #pragma unroll
        for (int j = 0; j < 8; j++) v[j] = tile[t8 + j][d];
        *reinterpret_cast<bf16x8*>(&Vtt[(((long)b * 64 + tt) * 128 + d) * 64 + t8]) = v;
    }
}

// ---- causal flash attention: 64-row q-tiles, paired; 8 waves = 2 qs x 4 kvq ----
// Block (v,b): phase1 qt=v, phase2 qt=63-v (qt in [0,64), 64 q-rows). Per phase the
// kv range [0,(qt+1)*64) is processed in KVB=128 iteration tiles: nIt = ceil((qt+1)/2);
// pairs sum to exactly 33 iterations per block (256 blocks = 1/CU, uniform).
// Per iteration ONE contiguous 64KB tile-set (K 128x256B rows + 2 tile-major Vtt tiles)
// is staged via global_load_lds, shared by all 8 waves. Counted vmcnt(8), stage-ahead-2,
// drain only at item end (T4). Quarters merge in-LDS; out written directly.
// NOTE: LDS buffer pointers are computed from runtime indices (smem + bi*32768) --
// constant-initialized pointer arrays into LDS fail gfx950 codegen (R8 lesson).
__global__ __launch_bounds__(512, 2) void attn_kernel(const bf16* __restrict__ Q,
                                                      const bf16* __restrict__ K,
                                                      const bf16* __restrict__ Vtt,
                                                      float* __restrict__ out) {
    __shared__ __align__(1024) char smem[131072];        // kbuf[2]@0/32K, vbuf[2]@64K/96K
    __shared__ float mlb[6 * 64];
    const int tid = threadIdx.x;
    const int wave = tid >> 6, lane = tid & 63;
    const int c = lane & 31, hi = lane >> 5;
    const int qs = wave >> 2, kvq = wave & 3;
    const int kswz = ((c & 7) << 4) ^ (((c >> 3) & 1) << 7);
    const int vswz = (c & 7) << 4;
    const int v = blockIdx.x >> 3, b = blockIdx.x & 7;   // batch pinned to XCD
    const long base = (long)b * TT * 128;
    const char* Kb = (const char*)(K + base);
    const char* Vb = (const char*)Vtt + (long)b * (64 * 16384);

    int kOff[4], vOff[4], lOff[4];
    #pragma unroll
    for (int i = 0; i < 4; i++) {
        int D = wave * 4096 + i * 1024 + lane * 16;      // linear dest byte in 32KB
        kOff[i] = (D & ~255) | ((D & 255) ^ (((D >> 8) & 7) << 4) ^ (((D >> 11) & 1) << 7));
        vOff[i] = (D & ~127) | ((D & 127) ^ (((D >> 7) & 7) << 4));
        lOff[i] = wave * 4096 + i * 1024;                // HW adds lane*16
    }

    #pragma unroll 1
    for (int ph = 0; ph < 2; ph++) {
        const int qt = ph ? 63 - v : v;
        const int nIt = (qt + 2) >> 1;                   // ceil((qt+1)/2) KVB=128 tiles
        const int q0w = qt * 64 + qs * 32;
        const int qa = q0w + c;

        bf16x8 qf[8];
        #pragma unroll
        for (int dw = 0; dw < 8; dw++)
            qf[dw] = *reinterpret_cast<const bf16x8*>(&Q[base + (long)qa * 128 + dw * 16 + hi * 8]);

        f32x16 O[4] = {};
        float m = -__builtin_inff(), l = 0.f;

        {   // prologue: stage tiles 0 (and 1) -> stage-ahead-2
            #pragma unroll
            for (int i = 0; i < 4; i++) {
                gload16(Kb + kOff[i], smem + lOff[i]);
                gload16(Vb + vOff[i], smem + 65536 + lOff[i]);
            }
            if (nIt > 1) {
                #pragma unroll
                for (int i = 0; i < 4; i++) {
                    gload16(Kb + 32768 + kOff[i], smem + 32768 + lOff[i]);
                    gload16(Vb + 32768 + vOff[i], smem + 98304 + lOff[i]);
                }
            }
        }

        #pragma unroll 1
        for (int it = 0; it < nIt; it++) {
            const int bi = it & 1;
            char* kBuf = smem + bi * 32768;              // runtime-indexed (no const-init LDS ptr)
            char* vBuf = smem + 65536 + bi * 32768;
            if (it + 1 < nIt) asm volatile("s_waitcnt vmcnt(8)" ::: "memory");
            else              asm volatile("s_waitcnt vmcnt(0)" ::: "memory");
            __builtin_amdgcn_s_barrier();                // tile it visible to all waves

            const int kv0 = it * 128 + kvq * 32;
            if (kv0 <= q0w) {                            // 32-aligned => no empty q-rows
                const char* kb = kBuf + kvq * 8192;
                const char* vb = vBuf + (kvq >> 1) * 16384;
                const int vcol0 = (kvq & 1) * 64;        // byte offset of wave's 32 kv
                f32x16 S = {};
                __builtin_amdgcn_s_setprio(1);
                #pragma unroll
                for (int dw = 0; dw < 8; dw++) {         // S^T = K Q^T
                    bf16x8 kf = *reinterpret_cast<const bf16x8*>(
                        kb + c * 256 + ((dw * 32 + hi * 16) ^ kswz));
                    S = __builtin_amdgcn_mfma_f32_32x32x16_bf16(kf, qf[dw], S, 0, 0, 0);
                }
                __builtin_amdgcn_s_setprio(0);
                if (kv0 == q0w) {                        // diagonal tile: causal mask
                    #pragma unroll
                    for (int i = 0; i < 16; i++) {
                        int kvr = kv0 + (i & 3) + 8 * (i >> 2) + 4 * hi;
                        if (kvr > qa) S[i] = -__builtin_inff();
                    }
                }
                float t8[8];
                #pragma unroll
                for (int i = 0; i < 8; i++) t8[i] = fmaxf(S[i], S[i + 8]);
                float t4a = fmaxf(t8[0], t8[4]), t4b = fmaxf(t8[1], t8[5]);
                float t4c = fmaxf(t8[2], t8[6]), t4d = fmaxf(t8[3], t8[7]);
                float pm = fmaxf(fmaxf(t4a, t4b), fmaxf(t4c, t4d));
                pm = fmaxf(pm, __shfl_xor(pm, 32, 64));  // partner half (other 16 kv regs)
                if (!__all(pm - m <= 8.0f)) {            // defer-max
                    float mn = fmaxf(m, pm);
                    float fr = __expf(m - mn);
                    #pragma unroll
                    for (int dt = 0; dt < 4; dt++) O[dt] = O[dt] * fr;
                    l *= fr;
                    m = mn;
                }
                #pragma unroll
                for (int i = 0; i < 16; i++) S[i] = __expf(S[i] - m);
                float s8[8];
                #pragma unroll
                for (int i = 0; i < 8; i++) s8[i] = S[i] + S[i + 8];
                l += ((s8[0] + s8[4]) + (s8[1] + s8[5])) + ((s8[2] + s8[6]) + (s8[3] + s8[7]));

                bf16x8 pf[2];                            // P -> B-frags, sel-trick exchange
                #pragma unroll
                for (int wl = 0; wl < 2; wl++) {
                    const int i0 = 8 * wl;
                    unsigned L0 = pkbf(S[i0 + 0], S[i0 + 1]);
                    unsigned L1 = pkbf(S[i0 + 2], S[i0 + 3]);
                    unsigned H0 = pkbf(S[i0 + 4], S[i0 + 5]);
                    unsigned H1 = pkbf(S[i0 + 6], S[i0 + 7]);
                    unsigned sel0 = hi ? L0 : H0;        // offer what partner needs
                    unsigned sel1 = hi ? L1 : H1;
                    unsigned x0 = __shfl_xor((int)sel0, 32, 64);
                    unsigned x1 = __shfl_xor((int)sel1, 32, 64);
                    uint4 f;
                    f.x = hi ? x0 : L0;
                    f.y = hi ? x1 : L1;
                    f.z = hi ? H0 : x0;
                    f.w = hi ? H1 : x1;
                    pf[wl] = __builtin_bit_cast(bf16x8, f);
                }
                __builtin_amdgcn_s_setprio(1);
                #pragma unroll
                for (int wl = 0; wl < 2; wl++)           // O^T += V^T P
                    #pragma unroll
                    for (int dt = 0; dt < 4; dt++) {
                        bf16x8 vf = *reinterpret_cast<const bf16x8*>(
                            vb + (dt * 32 + c) * 128 + ((vcol0 + wl * 32 + hi * 16) ^ vswz));
                        O[dt] = __builtin_amdgcn_mfma_f32_32x32x16_bf16(vf, pf[wl], O[dt], 0, 0, 0);
                    }
                __builtin_amdgcn_s_setprio(0);
            }
            __builtin_amdgcn_s_barrier();                // all waves done reading buf bi
            if (it + 2 < nIt) {                          // stage it+2 into freed buffer
                const char* Ks = Kb + (long)(it + 2) * 32768;
                const char* Vs = Vb + (long)(it + 2) * 32768;
                #pragma unroll
                for (int i = 0; i < 4; i++) {
                    gload16(Ks + kOff[i], kBuf + lOff[i]);
                    gload16(Vs + vOff[i], vBuf + lOff[i]);
                }
            }
        }

        l += __shfl_xor(l, 32, 64);                      // combine partner kv-reg halves

        if (kvq != 0) {                                  // quarters 1..3 publish partials
            const int sl = qs * 3 + (kvq - 1);
            char* om = smem + sl * 16384;
            #pragma unroll
            for (int dt = 0; dt < 4; dt++)
                #pragma unroll
                for (int g = 0; g < 4; g++) {
                    float4 w4 = { O[dt][4 * g + 0], O[dt][4 * g + 1],
                                  O[dt][4 * g + 2], O[dt][4 * g + 3] };
                    *reinterpret_cast<float4*>(
                        om + c * 512 + ((dt * 128 + g * 32 + hi * 16) ^ ((c & 7) << 4))) = w4;
                }
            if (hi == 0) { mlb[sl * 64 + c] = m; mlb[sl * 64 + 32 + c] = l; }
        }
        __syncthreads();
        if (kvq == 0) {                                  // quarter 0 merges + writes out
            float mq[3], lq[3];
            float mx = m;                                // kvq0 always has data (finite)
            #pragma unroll
            for (int p = 0; p < 3; p++) {
                const int sl = qs * 3 + p;
                mq[p] = mlb[sl * 64 + c];
                lq[p] = mlb[sl * 64 + 32 + c];
                mx = fmaxf(mx, mq[p]);
            }
            float f0 = __expf(m - mx);
            float lt = l * f0;
            float fq[3];
            #pragma unroll
            for (int p = 0; p < 3; p++) { fq[p] = __expf(mq[p] - mx); lt += lq[p] * fq[p]; }
            float linv = 1.0f / lt;
            #pragma unroll
            for (int dt = 0; dt < 4; dt++)
                #pragma unroll
                for (int g = 0; g < 4; g++) {
                    float4 r;
                    r.x = O[dt][4 * g + 0] * f0;
                    r.y = O[dt][4 * g + 1] * f0;
                    r.z = O[dt][4 * g + 2] * f0;
                    r.w = O[dt][4 * g + 3] * f0;
                    #pragma unroll
                    for (int p = 0; p < 3; p++) {
                        const char* om = smem + (qs * 3 + p) * 16384;
                        float4 o1 = *reinterpret_cast<const float4*>(
                            om + c * 512 + ((dt * 128 + g * 32 + hi * 16) ^ ((c & 7) << 4)));
                        r.x += o1.x * fq[p]; r.y += o1.y * fq[p];
                        r.z += o1.z * fq[p]; r.w += o1.w * fq[p];
                    }
                    r.x *= linv; r.y *= linv; r.z *= linv; r.w *= linv;
                    *reinterpret_cast<float4*>(
                        &out[base + (long)qa * 128 + dt * 32 + 8 * g + 4 * hi]) = r;
                }
        }
        __syncthreads();                                 // LDS safe before next phase stages
    }
}

extern "C" void kernel_launch(void* const* d_in, const int* in_sizes, int n_in,
                              void* d_out, int out_size, void* d_ws, size_t ws_size,
                              hipStream_t stream) {
    const float* x  = (const float*)d_in[0];
    const float* Wq = (const float*)d_in[1];
    const float* Wk = (const float*)d_in[2];
    const float* Wv = (const float*)d_in[3];
    float* out = (float*)d_out;
    bf16* Q   = (bf16*)d_ws;                      // [32768][128]
    bf16* K   = Q   + (size_t)32768 * 128;
    bf16* V   = K   + (size_t)32768 * 128;
    bf16* Wt  = V   + (size_t)32768 * 128;        // [3][128][1024]
    bf16* Vtt = Wt  + (size_t)3 * 128 * 1024;     // [8][64][128][64] tile-major
    wt_kernel<<<96, 256, 0, stream>>>(Wq, Wk, Wv, Wt);
    qkv_kernel<<<512, 256, 0, stream>>>(x, Wt, Q, K, V);
    vtrans_kernel<<<dim3(64, 8), 256, 0, stream>>>(V, Vtt);
    attn_kernel<<<256, 512, 0, stream>>>(Q, K, Vtt, out);
}